// Round 6
// baseline (2080.881 us; speedup 1.0000x reference)
//
#include <hip/hip_runtime.h>

// B=512, T=1024, I=H=64, 3H=192.
#define NB 512
#define NT 1024
#define NH 64
#define G3 192
#define CH 8            // timesteps staged per superstep
#define NCH (NT / CH)   // 128 supersteps

// One block per batch element, one GRU layer per pass. 384 threads = 6 waves:
// waves 0-2 (tid<192)  -> Wih rows, v = x_t
// waves 3-5 (tid>=192) -> Whh rows, v = h
// Round-5 evidence: per-thread ds_read_b128 broadcast of v saturates the LDS
// pipe (~2100 cyc/step). This version holds v in lane registers (one
// ds_read_b32 per wave) and broadcasts elements via v_readlane -> SGPR,
// feeding v_fma_f32's single legal SGPR operand. Weights stay pinned in the
// register file (VGPR or AGPR) via the opaque asm.
__global__ __launch_bounds__(384, 2) void gru_layer(
    const float* in,                      // [B][T][64]  (aliases hseq in pass 2)
    const float* __restrict__ Wih, const float* __restrict__ Whh,   // [192][64]
    const float* __restrict__ bih, const float* __restrict__ bhh,   // [192]
    float* hseq)                          // [B][T][64] out
{
    const int tid  = threadIdx.x;
    const int lane = tid & 63;
    const int b    = blockIdx.x;
    const bool isIh = (tid < G3);
    const int  row  = isIh ? tid : (tid - G3);

    __shared__ __align__(16) float xin[2][CH * NH]; // double-buffered input chunks
    __shared__ __align__(16) float hbuf[NH];        // current hidden state
    __shared__ __align__(16) float hist[CH * NH];   // h outputs of this superstep
    __shared__ __align__(16) float g[384];          // gx rows 0..191 | gh rows 192..383

    // ---- weight row -> register file (one-time), pinned via opaque asm ----
    float w[64];
    {
        const float4* src = (const float4*)((isIh ? Wih : Whh) + row * 64);
        #pragma unroll
        for (int j = 0; j < 16; ++j) {
            float4 t = src[j];
            w[4*j+0] = t.x; w[4*j+1] = t.y; w[4*j+2] = t.z; w[4*j+3] = t.w;
        }
    }
    #pragma unroll
    for (int j = 0; j < 64; ++j) asm volatile("" : "+v"(w[j]));

    const float bias = isIh ? bih[row] : bhh[row];

    const float* inb  = in   + (size_t)b * NT * NH;
    float*       hout = hseq + (size_t)b * NT * NH;

    // stage chunk 0 (128 float4, coalesced)
    if (tid < 128) ((float4*)&xin[0][0])[tid] = ((const float4*)inb)[tid];
    if (tid < NH) hbuf[tid] = 0.0f;
    float hreg = 0.0f;                    // gates thread (tid<64) keeps h_old[tid]
    __syncthreads();

    for (int tc = 0; tc < NCH; ++tc) {
        // issue prefetch of next chunk early; committed at superstep end.
        float4 pf;
        if (tid < 128) {
            int tcn = (tc + 1) & (NCH - 1);     // wraps on last iter (dead data)
            pf = ((const float4*)(inb + (size_t)tcn * CH * NH))[tid];
        }

        for (int s = 0; s < CH; ++s) {
            // ---- v into lane registers: ONE ds_read_b32 per wave ----
            float vlane = isIh ? xin[tc & 1][s * NH + lane] : hbuf[lane];
            const int vi = __float_as_int(vlane);

            // ---- matvec: 64 x (readlane -> SGPR, fma). 4 acc chains for ILP.
            float a0 = 0.f, a1 = 0.f, a2 = 0.f, a3 = 0.f;
            #pragma unroll
            for (int k = 0; k < 16; ++k) {
                float e0 = __int_as_float(__builtin_amdgcn_readlane(vi, 4*k+0));
                float e1 = __int_as_float(__builtin_amdgcn_readlane(vi, 4*k+1));
                float e2 = __int_as_float(__builtin_amdgcn_readlane(vi, 4*k+2));
                float e3 = __int_as_float(__builtin_amdgcn_readlane(vi, 4*k+3));
                a0 = fmaf(w[4*k+0], e0, a0);
                a1 = fmaf(w[4*k+1], e1, a1);
                a2 = fmaf(w[4*k+2], e2, a2);
                a3 = fmaf(w[4*k+3], e3, a3);
            }
            g[tid] = ((a0 + a1) + (a2 + a3)) + bias;
            __syncthreads();

            // ---- gates (threads 0..63; h_old held in hreg) ----
            if (tid < NH) {
                float xr = g[tid],      xz = g[NH + tid],      xn = g[2*NH + tid];
                float hr = g[G3 + tid], hz = g[G3 + NH + tid], hn = g[G3 + 2*NH + tid];
                float r = __builtin_amdgcn_rcpf(1.0f + __expf(-(xr + hr)));
                float z = __builtin_amdgcn_rcpf(1.0f + __expf(-(xz + hz)));
                float a = xn + r * hn;                    // bhh_n rides inside hn
                float n = 1.0f - 2.0f * __builtin_amdgcn_rcpf(__expf(2.0f * a) + 1.0f);
                hreg = (1.0f - z) * n + z * hreg;
                hbuf[tid] = hreg;
                hist[s * NH + tid] = hreg;     // global store deferred to superstep end
            }
            __syncthreads();
        }

        // flush this superstep's h rows (coalesced), commit prefetched chunk
        if (tid < 128) {
            ((float4*)(hout + (size_t)tc * CH * NH))[tid] = ((const float4*)hist)[tid];
            ((float4*)&xin[(tc + 1) & 1][0])[tid] = pf;
        }
        __syncthreads();
    }
}

// out[bt] = dot(hseq[bt][:], fcw) + fcb  -- memory-bound, trivially parallel.
__global__ __launch_bounds__(256) void head_k(
    const float* __restrict__ hseq, const float* __restrict__ fcw,
    const float* __restrict__ fcb, float* __restrict__ out)
{
    int i = blockIdx.x * 256 + threadIdx.x;         // bt in [0, B*T)
    const float4* hp = (const float4*)(hseq + (size_t)i * NH);
    const float4* wp = (const float4*)fcw;
    float a0 = 0.f, a1 = 0.f, a2 = 0.f, a3 = 0.f;
    #pragma unroll
    for (int j = 0; j < 16; ++j) {
        float4 h = hp[j], w = wp[j];
        a0 = fmaf(h.x, w.x, a0);
        a1 = fmaf(h.y, w.y, a1);
        a2 = fmaf(h.z, w.z, a2);
        a3 = fmaf(h.w, w.w, a3);
    }
    out[i] = ((a0 + a1) + (a2 + a3)) + fcb[0];
}

extern "C" void kernel_launch(void* const* d_in, const int* in_sizes, int n_in,
                              void* d_out, int out_size, void* d_ws, size_t ws_size,
                              hipStream_t stream) {
    (void)in_sizes; (void)n_in; (void)out_size; (void)ws_size;
    const float* x    = (const float*)d_in[0];
    const float* Wih0 = (const float*)d_in[1];
    const float* Whh0 = (const float*)d_in[2];
    const float* bih0 = (const float*)d_in[3];
    const float* bhh0 = (const float*)d_in[4];
    const float* Wih1 = (const float*)d_in[5];
    const float* Whh1 = (const float*)d_in[6];
    const float* bih1 = (const float*)d_in[7];
    const float* bhh1 = (const float*)d_in[8];
    const float* fcw  = (const float*)d_in[9];
    const float* fcb  = (const float*)d_in[10];

    float* hseq = (float*)d_ws;   // B*T*H*4 = 134.2 MB of workspace

    gru_layer<<<NB, 384, 0, stream>>>(x,    Wih0, Whh0, bih0, bhh0, hseq);
    gru_layer<<<NB, 384, 0, stream>>>(hseq, Wih1, Whh1, bih1, bhh1, hseq);
    head_k<<<2048, 256, 0, stream>>>(hseq, fcw, fcb, (float*)d_out);
}

// Round 7
// 1784.275 us; speedup vs baseline: 1.1662x; 1.1662x over previous
//
#include <hip/hip_runtime.h>

// B=512, T=1024, I=H=64, 3H=192.
#define NT 1024
#define NH 64
#define BT 16            // batch tile per block
#define NBLK 32          // 512 / BT

typedef short short8 __attribute__((ext_vector_type(8)));
typedef float f32x4 __attribute__((ext_vector_type(4)));

__device__ __forceinline__ unsigned short f2bf(float f) {   // RNE f32->bf16
    unsigned int u = __float_as_uint(f);
    u += 0x7FFF + ((u >> 16) & 1);
    return (unsigned short)(u >> 16);
}
__device__ __forceinline__ float bf2f(unsigned short s) {
    return __uint_as_float(((unsigned int)s) << 16);
}
__device__ __forceinline__ short8 pack8(float4 a, float4 b) {
    short8 s;
    s[0] = (short)f2bf(a.x); s[1] = (short)f2bf(a.y);
    s[2] = (short)f2bf(a.z); s[3] = (short)f2bf(a.w);
    s[4] = (short)f2bf(b.x); s[5] = (short)f2bf(b.y);
    s[6] = (short)f2bf(b.z); s[7] = (short)f2bf(b.w);
    return s;
}

#define MFMA(a, b, c) __builtin_amdgcn_mfma_f32_16x16x32_bf16((a), (b), (c), 0, 0, 0)

// Fused 2-layer GRU, 16 batches/block, 4 waves (wave w owns gate/hidden cols
// 16w..16w+15 of all three gates: tiles n0 = 64*g + 16*w).
// mfma_f32_16x16x32_bf16 layouts (m89/m91-verified family):
//   A (arg0): row m = lane&15,  k = 8*(lane>>4)+j   (8 bf16 contiguous in k)
//   B (arg1): col n = lane&15,  k = 8*(lane>>4)+j
//   C/D:      col n = lane&15,  row m = 4*(lane>>4)+reg
// h carried in f32 lane registers (gate distribution); bf16 only enters as
// MFMA operands. Whh split hi+lo bf16 to suppress systematic recurrent drift.
__global__ __launch_bounds__(256, 1) void gru2_mfma(
    const float* __restrict__ x,
    const float* __restrict__ Wih0, const float* __restrict__ Whh0,
    const float* __restrict__ bih0, const float* __restrict__ bhh0,
    const float* __restrict__ Wih1, const float* __restrict__ Whh1,
    const float* __restrict__ bih1, const float* __restrict__ bhh1,
    float* __restrict__ hseq)
{
    const int tid = threadIdx.x;
    const int w   = tid >> 6;      // wave 0..3
    const int l   = tid & 63;
    const int l15 = l & 15;
    const int lk  = l >> 4;        // k-group 0..3
    const int bb0 = blockIdx.x * BT;
    const int j   = 16 * w + l15;  // hidden/gate column owned by this lane

    __shared__ __align__(16) unsigned short h0t[16 * 64];  // swizzled bf16 tiles
    __shared__ __align__(16) unsigned short h1t[16 * 64];

    // ---- weight B-fragments (one-time) ----
    short8 fih0[3][2], fih1[3][2];
    short8 fhh0h[3][2], fhh0l[3][2], fhh1h[3][2], fhh1l[3][2];
    #pragma unroll
    for (int g = 0; g < 3; ++g) {
        #pragma unroll
        for (int kh = 0; kh < 2; ++kh) {
            const int row = 64 * g + 16 * w + l15;
            const int col = 32 * kh + 8 * lk;
            {
                const float* p = Wih0 + row * 64 + col;
                fih0[g][kh] = pack8(((const float4*)p)[0], ((const float4*)p)[1]);
            }
            {
                const float* p = Wih1 + row * 64 + col;
                fih1[g][kh] = pack8(((const float4*)p)[0], ((const float4*)p)[1]);
            }
            {
                const float* p = Whh0 + row * 64 + col;
                float4 a = ((const float4*)p)[0], b = ((const float4*)p)[1];
                float v[8] = {a.x, a.y, a.z, a.w, b.x, b.y, b.z, b.w};
                short8 hi, lo;
                #pragma unroll
                for (int e = 0; e < 8; ++e) {
                    unsigned short hb = f2bf(v[e]);
                    hi[e] = (short)hb;
                    lo[e] = (short)f2bf(v[e] - bf2f(hb));
                }
                fhh0h[g][kh] = hi; fhh0l[g][kh] = lo;
            }
            {
                const float* p = Whh1 + row * 64 + col;
                float4 a = ((const float4*)p)[0], b = ((const float4*)p)[1];
                float v[8] = {a.x, a.y, a.z, a.w, b.x, b.y, b.z, b.w};
                short8 hi, lo;
                #pragma unroll
                for (int e = 0; e < 8; ++e) {
                    unsigned short hb = f2bf(v[e]);
                    hi[e] = (short)hb;
                    lo[e] = (short)f2bf(v[e] - bf2f(hb));
                }
                fhh1h[g][kh] = hi; fhh1l[g][kh] = lo;
            }
        }
    }

    // ---- biases (r,z fold bih+bhh; n keeps them separate: n = tanh(xn + r*hn)) ----
    const float br0  = bih0[j] + bhh0[j];
    const float bz0  = bih0[64 + j] + bhh0[64 + j];
    const float bxn0 = bih0[128 + j];
    const float bhn0 = bhh0[128 + j];
    const float br1  = bih1[j] + bhh1[j];
    const float bz1  = bih1[64 + j] + bhh1[64 + j];
    const float bxn1 = bih1[128 + j];
    const float bhn1 = bhh1[128 + j];

    // ---- state ----
    float h0s[4] = {0.f, 0.f, 0.f, 0.f}, h1s[4] = {0.f, 0.f, 0.f, 0.f};
    short8 h0f[2], h1f[2];
    #pragma unroll
    for (int e = 0; e < 8; ++e) { h0f[0][e] = 0; h0f[1][e] = 0; h1f[0][e] = 0; h1f[1][e] = 0; }

    // ---- x A-frag source: lane reads rows (batch) = l15, k-chunk = 8*lk ----
    const float* xlane = x + (size_t)(bb0 + l15) * NT * 64 + 8 * lk;
    float4 xa[4], xb[4];
    #pragma unroll
    for (int kh = 0; kh < 2; ++kh) {
        xa[2 * kh + 0] = ((const float4*)(xlane + 32 * kh))[0];
        xa[2 * kh + 1] = ((const float4*)(xlane + 32 * kh))[1];
    }

    for (int t = 0; t < NT; ++t) {
        // prefetch x(t+1) — independent of the recurrence, covers HBM latency
        {
            int tn = (t + 1 < NT) ? t + 1 : NT - 1;
            const float* p = xlane + (size_t)tn * 64;
            #pragma unroll
            for (int kh = 0; kh < 2; ++kh) {
                xb[2 * kh + 0] = ((const float4*)(p + 32 * kh))[0];
                xb[2 * kh + 1] = ((const float4*)(p + 32 * kh))[1];
            }
        }
        short8 xf0 = pack8(xa[0], xa[1]);
        short8 xf1 = pack8(xa[2], xa[3]);

        // ================= layer 0 =================
        f32x4 ar  = {br0, br0, br0, br0};
        f32x4 az  = {bz0, bz0, bz0, bz0};
        f32x4 axn = {bxn0, bxn0, bxn0, bxn0};
        f32x4 ahn = {bhn0, bhn0, bhn0, bhn0};
        ar  = MFMA(xf0, fih0[0][0], ar);   az  = MFMA(xf0, fih0[1][0], az);
        axn = MFMA(xf0, fih0[2][0], axn);
        ar  = MFMA(xf1, fih0[0][1], ar);   az  = MFMA(xf1, fih0[1][1], az);
        axn = MFMA(xf1, fih0[2][1], axn);
        ar  = MFMA(h0f[0], fhh0h[0][0], ar);  az  = MFMA(h0f[0], fhh0h[1][0], az);
        ahn = MFMA(h0f[0], fhh0h[2][0], ahn);
        ar  = MFMA(h0f[1], fhh0h[0][1], ar);  az  = MFMA(h0f[1], fhh0h[1][1], az);
        ahn = MFMA(h0f[1], fhh0h[2][1], ahn);
        ar  = MFMA(h0f[0], fhh0l[0][0], ar);  az  = MFMA(h0f[0], fhh0l[1][0], az);
        ahn = MFMA(h0f[0], fhh0l[2][0], ahn);
        ar  = MFMA(h0f[1], fhh0l[0][1], ar);  az  = MFMA(h0f[1], fhh0l[1][1], az);
        ahn = MFMA(h0f[1], fhh0l[2][1], ahn);

        #pragma unroll
        for (int i = 0; i < 4; ++i) {
            float r = __builtin_amdgcn_rcpf(1.0f + __expf(-ar[i]));
            float z = __builtin_amdgcn_rcpf(1.0f + __expf(-az[i]));
            float a = axn[i] + r * ahn[i];
            float n = 1.0f - 2.0f * __builtin_amdgcn_rcpf(__expf(2.0f * a) + 1.0f);
            h0s[i] = (1.0f - z) * n + z * h0s[i];
        }
        // h0 -> swizzled bf16 tile
        #pragma unroll
        for (int i = 0; i < 4; ++i) {
            int m = 4 * lk + i;
            int off = (m * 128 + j * 2) ^ ((m & 7) << 4);
            h0t[off >> 1] = f2bf(h0s[i]);
        }
        __syncthreads();
        #pragma unroll
        for (int kh = 0; kh < 2; ++kh) {
            int off = (l15 * 128 + 64 * kh + 16 * lk) ^ ((l15 & 7) << 4);
            h0f[kh] = *(const short8*)((const char*)h0t + off);
        }

        // ================= layer 1 (input = h0f) =================
        f32x4 cr  = {br1, br1, br1, br1};
        f32x4 cz  = {bz1, bz1, bz1, bz1};
        f32x4 cxn = {bxn1, bxn1, bxn1, bxn1};
        f32x4 chn = {bhn1, bhn1, bhn1, bhn1};
        cr  = MFMA(h0f[0], fih1[0][0], cr);   cz  = MFMA(h0f[0], fih1[1][0], cz);
        cxn = MFMA(h0f[0], fih1[2][0], cxn);
        cr  = MFMA(h0f[1], fih1[0][1], cr);   cz  = MFMA(h0f[1], fih1[1][1], cz);
        cxn = MFMA(h0f[1], fih1[2][1], cxn);
        cr  = MFMA(h1f[0], fhh1h[0][0], cr);  cz  = MFMA(h1f[0], fhh1h[1][0], cz);
        chn = MFMA(h1f[0], fhh1h[2][0], chn);
        cr  = MFMA(h1f[1], fhh1h[0][1], cr);  cz  = MFMA(h1f[1], fhh1h[1][1], cz);
        chn = MFMA(h1f[1], fhh1h[2][1], chn);
        cr  = MFMA(h1f[0], fhh1l[0][0], cr);  cz  = MFMA(h1f[0], fhh1l[1][0], cz);
        chn = MFMA(h1f[0], fhh1l[2][0], chn);
        cr  = MFMA(h1f[1], fhh1l[0][1], cr);  cz  = MFMA(h1f[1], fhh1l[1][1], cz);
        chn = MFMA(h1f[1], fhh1l[2][1], chn);

        #pragma unroll
        for (int i = 0; i < 4; ++i) {
            float r = __builtin_amdgcn_rcpf(1.0f + __expf(-cr[i]));
            float z = __builtin_amdgcn_rcpf(1.0f + __expf(-cz[i]));
            float a = cxn[i] + r * chn[i];
            float n = 1.0f - 2.0f * __builtin_amdgcn_rcpf(__expf(2.0f * a) + 1.0f);
            h1s[i] = (1.0f - z) * n + z * h1s[i];
        }
        // h1 -> global (f32, for head) and swizzled tile (next step's A-frag)
        #pragma unroll
        for (int i = 0; i < 4; ++i) {
            int m = 4 * lk + i;
            hseq[((size_t)(bb0 + m) * NT + t) * 64 + j] = h1s[i];
            int off = (m * 128 + j * 2) ^ ((m & 7) << 4);
            h1t[off >> 1] = f2bf(h1s[i]);
        }
        __syncthreads();
        #pragma unroll
        for (int kh = 0; kh < 2; ++kh) {
            int off = (l15 * 128 + 64 * kh + 16 * lk) ^ ((l15 & 7) << 4);
            h1f[kh] = *(const short8*)((const char*)h1t + off);
        }

        #pragma unroll
        for (int q = 0; q < 4; ++q) xa[q] = xb[q];
    }
}

// out[bt] = dot(hseq[bt][:], fcw) + fcb  -- memory-bound, trivially parallel.
__global__ __launch_bounds__(256) void head_k(
    const float* __restrict__ hseq, const float* __restrict__ fcw,
    const float* __restrict__ fcb, float* __restrict__ out)
{
    int i = blockIdx.x * 256 + threadIdx.x;          // bt in [0, B*T)
    const float4* hp = (const float4*)(hseq + (size_t)i * NH);
    const float4* wp = (const float4*)fcw;
    float a0 = 0.f, a1 = 0.f, a2 = 0.f, a3 = 0.f;
    #pragma unroll
    for (int q = 0; q < 16; ++q) {
        float4 h = hp[q], v = wp[q];
        a0 = fmaf(h.x, v.x, a0);
        a1 = fmaf(h.y, v.y, a1);
        a2 = fmaf(h.z, v.z, a2);
        a3 = fmaf(h.w, v.w, a3);
    }
    out[i] = ((a0 + a1) + (a2 + a3)) + fcb[0];
}

extern "C" void kernel_launch(void* const* d_in, const int* in_sizes, int n_in,
                              void* d_out, int out_size, void* d_ws, size_t ws_size,
                              hipStream_t stream) {
    (void)in_sizes; (void)n_in; (void)out_size; (void)ws_size;
    const float* x    = (const float*)d_in[0];
    const float* Wih0 = (const float*)d_in[1];
    const float* Whh0 = (const float*)d_in[2];
    const float* bih0 = (const float*)d_in[3];
    const float* bhh0 = (const float*)d_in[4];
    const float* Wih1 = (const float*)d_in[5];
    const float* Whh1 = (const float*)d_in[6];
    const float* bih1 = (const float*)d_in[7];
    const float* bhh1 = (const float*)d_in[8];
    const float* fcw  = (const float*)d_in[9];
    const float* fcb  = (const float*)d_in[10];

    float* hseq = (float*)d_ws;   // B*T*H*4 = 134.2 MB workspace

    gru2_mfma<<<NBLK, 256, 0, stream>>>(x, Wih0, Whh0, bih0, bhh0,
                                        Wih1, Whh1, bih1, bhh1, hseq);
    head_k<<<2048, 256, 0, stream>>>(hseq, fcw, fcb, (float*)d_out);
}

// Round 8
// 1328.180 us; speedup vs baseline: 1.5667x; 1.3434x over previous
//
#include <hip/hip_runtime.h>

// B=512, T=1024, I=H=64, 3H=192.
#define NT 1024
#define NH 64
#define BT 16            // batch tile per block
#define NBLK 32          // 512 / BT

typedef short short8 __attribute__((ext_vector_type(8)));
typedef float f32x4 __attribute__((ext_vector_type(4)));

__device__ __forceinline__ unsigned short f2bf(float f) {   // RNE f32->bf16
    unsigned int u = __float_as_uint(f);
    u += 0x7FFF + ((u >> 16) & 1);
    return (unsigned short)(u >> 16);
}
__device__ __forceinline__ float bf2f(unsigned short s) {
    return __uint_as_float(((unsigned int)s) << 16);
}
__device__ __forceinline__ short8 pack8(float4 a, float4 b) {
    short8 s;
    s[0] = (short)f2bf(a.x); s[1] = (short)f2bf(a.y);
    s[2] = (short)f2bf(a.z); s[3] = (short)f2bf(a.w);
    s[4] = (short)f2bf(b.x); s[5] = (short)f2bf(b.y);
    s[6] = (short)f2bf(b.z); s[7] = (short)f2bf(b.w);
    return s;
}

#define MFMA(a, b, c) __builtin_amdgcn_mfma_f32_16x16x32_bf16((a), (b), (c), 0, 0, 0)

// Raw barrier that does NOT drain vmcnt (hipcc's __syncthreads emits
// s_waitcnt vmcnt(0) before s_barrier, which serialized the x-prefetch and
// hseq stores into every step -- the round-7 2500-cyc/step stall).
// LDS ordering: lgkmcnt(0) makes this wave's ds_writes visible pre-barrier;
// sched_barrier(0) fences compiler motion on both sides (guide rule #18).
__device__ __forceinline__ void block_sync_lds() {
    __builtin_amdgcn_sched_barrier(0);
    asm volatile("s_waitcnt lgkmcnt(0)" ::: "memory");
    __builtin_amdgcn_s_barrier();
    __builtin_amdgcn_sched_barrier(0);
}

// Fused 2-layer GRU, 16 batches/block, 4 waves (wave w owns gate/hidden cols
// 16w..16w+15 of all three gates: tiles n0 = 64*g + 16*w).
// mfma_f32_16x16x32_bf16 layouts (m89/m91-verified family):
//   A (arg0): row m = lane&15,  k = 8*(lane>>4)+j   (8 bf16 contiguous in k)
//   B (arg1): col n = lane&15,  k = 8*(lane>>4)+j
//   C/D:      col n = lane&15,  row m = 4*(lane>>4)+reg
// h carried in f32 lane registers; bf16 only enters as MFMA operands.
// Whh split hi+lo bf16 to suppress systematic recurrent drift.
__global__ __launch_bounds__(256, 1) void gru2_mfma(
    const float* __restrict__ x,
    const float* __restrict__ Wih0, const float* __restrict__ Whh0,
    const float* __restrict__ bih0, const float* __restrict__ bhh0,
    const float* __restrict__ Wih1, const float* __restrict__ Whh1,
    const float* __restrict__ bih1, const float* __restrict__ bhh1,
    float* __restrict__ hseq)
{
    const int tid = threadIdx.x;
    const int w   = tid >> 6;      // wave 0..3
    const int l   = tid & 63;
    const int l15 = l & 15;
    const int lk  = l >> 4;        // k-group 0..3
    const int bb0 = blockIdx.x * BT;
    const int j   = 16 * w + l15;  // hidden/gate column owned by this lane

    __shared__ __align__(16) unsigned short h0t[16 * 64];  // swizzled bf16 tiles
    __shared__ __align__(16) unsigned short h1t[16 * 64];

    // ---- weight B-fragments (one-time) ----
    short8 fih0[3][2], fih1[3][2];
    short8 fhh0h[3][2], fhh0l[3][2], fhh1h[3][2], fhh1l[3][2];
    #pragma unroll
    for (int g = 0; g < 3; ++g) {
        #pragma unroll
        for (int kh = 0; kh < 2; ++kh) {
            const int row = 64 * g + 16 * w + l15;
            const int col = 32 * kh + 8 * lk;
            {
                const float* p = Wih0 + row * 64 + col;
                fih0[g][kh] = pack8(((const float4*)p)[0], ((const float4*)p)[1]);
            }
            {
                const float* p = Wih1 + row * 64 + col;
                fih1[g][kh] = pack8(((const float4*)p)[0], ((const float4*)p)[1]);
            }
            {
                const float* p = Whh0 + row * 64 + col;
                float4 a = ((const float4*)p)[0], b = ((const float4*)p)[1];
                float v[8] = {a.x, a.y, a.z, a.w, b.x, b.y, b.z, b.w};
                short8 hi, lo;
                #pragma unroll
                for (int e = 0; e < 8; ++e) {
                    unsigned short hb = f2bf(v[e]);
                    hi[e] = (short)hb;
                    lo[e] = (short)f2bf(v[e] - bf2f(hb));
                }
                fhh0h[g][kh] = hi; fhh0l[g][kh] = lo;
            }
            {
                const float* p = Whh1 + row * 64 + col;
                float4 a = ((const float4*)p)[0], b = ((const float4*)p)[1];
                float v[8] = {a.x, a.y, a.z, a.w, b.x, b.y, b.z, b.w};
                short8 hi, lo;
                #pragma unroll
                for (int e = 0; e < 8; ++e) {
                    unsigned short hb = f2bf(v[e]);
                    hi[e] = (short)hb;
                    lo[e] = (short)f2bf(v[e] - bf2f(hb));
                }
                fhh1h[g][kh] = hi; fhh1l[g][kh] = lo;
            }
        }
    }

    // ---- biases (r,z fold bih+bhh; n keeps them separate: n = tanh(xn + r*hn)) ----
    const float br0  = bih0[j] + bhh0[j];
    const float bz0  = bih0[64 + j] + bhh0[64 + j];
    const float bxn0 = bih0[128 + j];
    const float bhn0 = bhh0[128 + j];
    const float br1  = bih1[j] + bhh1[j];
    const float bz1  = bih1[64 + j] + bhh1[64 + j];
    const float bxn1 = bih1[128 + j];
    const float bhn1 = bhh1[128 + j];

    // ---- state ----
    float h0s[4] = {0.f, 0.f, 0.f, 0.f}, h1s[4] = {0.f, 0.f, 0.f, 0.f};
    short8 h0f[2], h1f[2];
    #pragma unroll
    for (int e = 0; e < 8; ++e) { h0f[0][e] = 0; h0f[1][e] = 0; h1f[0][e] = 0; h1f[1][e] = 0; }

    // ---- x A-frag source: lane reads rows (batch) = l15, k-chunk = 8*lk ----
    const float* xlane = x + (size_t)(bb0 + l15) * NT * 64 + 8 * lk;
    float4 xa[4], xb[4];
    #pragma unroll
    for (int kh = 0; kh < 2; ++kh) {
        xa[2 * kh + 0] = ((const float4*)(xlane + 32 * kh))[0];
        xa[2 * kh + 1] = ((const float4*)(xlane + 32 * kh))[1];
    }

    for (int t = 0; t < NT; ++t) {
        // prefetch x(t+1): issued here, consumed at loop end; with raw
        // barriers (no vmcnt drain) this now truly overlaps the whole step.
        {
            int tn = (t + 1 < NT) ? t + 1 : NT - 1;
            const float* p = xlane + (size_t)tn * 64;
            #pragma unroll
            for (int kh = 0; kh < 2; ++kh) {
                xb[2 * kh + 0] = ((const float4*)(p + 32 * kh))[0];
                xb[2 * kh + 1] = ((const float4*)(p + 32 * kh))[1];
            }
        }
        short8 xf0 = pack8(xa[0], xa[1]);
        short8 xf1 = pack8(xa[2], xa[3]);

        // ================= layer 0 =================
        f32x4 ar  = {br0, br0, br0, br0};
        f32x4 az  = {bz0, bz0, bz0, bz0};
        f32x4 axn = {bxn0, bxn0, bxn0, bxn0};
        f32x4 ahn = {bhn0, bhn0, bhn0, bhn0};
        ar  = MFMA(xf0, fih0[0][0], ar);   az  = MFMA(xf0, fih0[1][0], az);
        axn = MFMA(xf0, fih0[2][0], axn);
        ar  = MFMA(xf1, fih0[0][1], ar);   az  = MFMA(xf1, fih0[1][1], az);
        axn = MFMA(xf1, fih0[2][1], axn);
        ar  = MFMA(h0f[0], fhh0h[0][0], ar);  az  = MFMA(h0f[0], fhh0h[1][0], az);
        ahn = MFMA(h0f[0], fhh0h[2][0], ahn);
        ar  = MFMA(h0f[1], fhh0h[0][1], ar);  az  = MFMA(h0f[1], fhh0h[1][1], az);
        ahn = MFMA(h0f[1], fhh0h[2][1], ahn);
        ar  = MFMA(h0f[0], fhh0l[0][0], ar);  az  = MFMA(h0f[0], fhh0l[1][0], az);
        ahn = MFMA(h0f[0], fhh0l[2][0], ahn);
        ar  = MFMA(h0f[1], fhh0l[0][1], ar);  az  = MFMA(h0f[1], fhh0l[1][1], az);
        ahn = MFMA(h0f[1], fhh0l[2][1], ahn);

        #pragma unroll
        for (int i = 0; i < 4; ++i) {
            float r = __builtin_amdgcn_rcpf(1.0f + __expf(-ar[i]));
            float z = __builtin_amdgcn_rcpf(1.0f + __expf(-az[i]));
            float a = axn[i] + r * ahn[i];
            float n = 1.0f - 2.0f * __builtin_amdgcn_rcpf(__expf(2.0f * a) + 1.0f);
            h0s[i] = (1.0f - z) * n + z * h0s[i];
        }
        // h0 -> swizzled bf16 tile
        #pragma unroll
        for (int i = 0; i < 4; ++i) {
            int m = 4 * lk + i;
            int off = (m * 128 + j * 2) ^ ((m & 7) << 4);
            h0t[off >> 1] = f2bf(h0s[i]);
        }
        block_sync_lds();
        #pragma unroll
        for (int kh = 0; kh < 2; ++kh) {
            int off = (l15 * 128 + 64 * kh + 16 * lk) ^ ((l15 & 7) << 4);
            h0f[kh] = *(const short8*)((const char*)h0t + off);
        }

        // ================= layer 1 (input = h0f) =================
        f32x4 cr  = {br1, br1, br1, br1};
        f32x4 cz  = {bz1, bz1, bz1, bz1};
        f32x4 cxn = {bxn1, bxn1, bxn1, bxn1};
        f32x4 chn = {bhn1, bhn1, bhn1, bhn1};
        cr  = MFMA(h0f[0], fih1[0][0], cr);   cz  = MFMA(h0f[0], fih1[1][0], cz);
        cxn = MFMA(h0f[0], fih1[2][0], cxn);
        cr  = MFMA(h0f[1], fih1[0][1], cr);   cz  = MFMA(h0f[1], fih1[1][1], cz);
        cxn = MFMA(h0f[1], fih1[2][1], cxn);
        cr  = MFMA(h1f[0], fhh1h[0][0], cr);  cz  = MFMA(h1f[0], fhh1h[1][0], cz);
        chn = MFMA(h1f[0], fhh1h[2][0], chn);
        cr  = MFMA(h1f[1], fhh1h[0][1], cr);  cz  = MFMA(h1f[1], fhh1h[1][1], cz);
        chn = MFMA(h1f[1], fhh1h[2][1], chn);
        cr  = MFMA(h1f[0], fhh1l[0][0], cr);  cz  = MFMA(h1f[0], fhh1l[1][0], cz);
        chn = MFMA(h1f[0], fhh1l[2][0], chn);
        cr  = MFMA(h1f[1], fhh1l[0][1], cr);  cz  = MFMA(h1f[1], fhh1l[1][1], cz);
        chn = MFMA(h1f[1], fhh1l[2][1], chn);

        #pragma unroll
        for (int i = 0; i < 4; ++i) {
            float r = __builtin_amdgcn_rcpf(1.0f + __expf(-cr[i]));
            float z = __builtin_amdgcn_rcpf(1.0f + __expf(-cz[i]));
            float a = cxn[i] + r * chn[i];
            float n = 1.0f - 2.0f * __builtin_amdgcn_rcpf(__expf(2.0f * a) + 1.0f);
            h1s[i] = (1.0f - z) * n + z * h1s[i];
        }
        // h1 -> global (f32, fire-and-forget; never waited) and swizzled tile
        #pragma unroll
        for (int i = 0; i < 4; ++i) {
            int m = 4 * lk + i;
            hseq[((size_t)(bb0 + m) * NT + t) * 64 + j] = h1s[i];
            int off = (m * 128 + j * 2) ^ ((m & 7) << 4);
            h1t[off >> 1] = f2bf(h1s[i]);
        }
        block_sync_lds();
        #pragma unroll
        for (int kh = 0; kh < 2; ++kh) {
            int off = (l15 * 128 + 64 * kh + 16 * lk) ^ ((l15 & 7) << 4);
            h1f[kh] = *(const short8*)((const char*)h1t + off);
        }

        #pragma unroll
        for (int q = 0; q < 4; ++q) xa[q] = xb[q];
    }
}

// out[bt] = dot(hseq[bt][:], fcw) + fcb  -- memory-bound, trivially parallel.
__global__ __launch_bounds__(256) void head_k(
    const float* __restrict__ hseq, const float* __restrict__ fcw,
    const float* __restrict__ fcb, float* __restrict__ out)
{
    int i = blockIdx.x * 256 + threadIdx.x;          // bt in [0, B*T)
    const float4* hp = (const float4*)(hseq + (size_t)i * NH);
    const float4* wp = (const float4*)fcw;
    float a0 = 0.f, a1 = 0.f, a2 = 0.f, a3 = 0.f;
    #pragma unroll
    for (int q = 0; q < 16; ++q) {
        float4 h = hp[q], v = wp[q];
        a0 = fmaf(h.x, v.x, a0);
        a1 = fmaf(h.y, v.y, a1);
        a2 = fmaf(h.z, v.z, a2);
        a3 = fmaf(h.w, v.w, a3);
    }
    out[i] = ((a0 + a1) + (a2 + a3)) + fcb[0];
}

extern "C" void kernel_launch(void* const* d_in, const int* in_sizes, int n_in,
                              void* d_out, int out_size, void* d_ws, size_t ws_size,
                              hipStream_t stream) {
    (void)in_sizes; (void)n_in; (void)out_size; (void)ws_size;
    const float* x    = (const float*)d_in[0];
    const float* Wih0 = (const float*)d_in[1];
    const float* Whh0 = (const float*)d_in[2];
    const float* bih0 = (const float*)d_in[3];
    const float* bhh0 = (const float*)d_in[4];
    const float* Wih1 = (const float*)d_in[5];
    const float* Whh1 = (const float*)d_in[6];
    const float* bih1 = (const float*)d_in[7];
    const float* bhh1 = (const float*)d_in[8];
    const float* fcw  = (const float*)d_in[9];
    const float* fcb  = (const float*)d_in[10];

    float* hseq = (float*)d_ws;   // B*T*H*4 = 134.2 MB workspace

    gru2_mfma<<<NBLK, 256, 0, stream>>>(x, Wih0, Whh0, bih0, bhh0,
                                        Wih1, Whh1, bih1, bhh1, hseq);
    head_k<<<2048, 256, 0, stream>>>(hseq, fcw, fcb, (float*)d_out);
}